// Round 1
// baseline (257.694 us; speedup 1.0000x reference)
//
#include <hip/hip_runtime.h>
#include <stdint.h>

// ---------------------------------------------------------------------------
// RoIHead: out = crop_and_resize(feature, rois) @ (W_fc @ [W_loc|W_score])
//                + (b_fc @ [W_loc|W_score] + [b_loc|b_score])
// Algebraic refactor: 413 GF -> 32 GF; memory-bound on the 411 MB W_fc read.
// ---------------------------------------------------------------------------

typedef float          f32x4 __attribute__((ext_vector_type(4)));
typedef __bf16         bfx8  __attribute__((ext_vector_type(8)));
typedef unsigned short u16x8 __attribute__((ext_vector_type(8)));

#define KBIG 25088   // 7*7*512
#define NMID 4096    // FC_OUT
#define NROIS 2000

// float -> bf16 round-to-nearest-even (finite inputs)
__device__ __forceinline__ unsigned short f2bf(float f) {
  unsigned int u = __float_as_uint(f);
  unsigned int r = (u + 0x7fffu + ((u >> 16) & 1u)) >> 16;
  return (unsigned short)r;
}

// async global->LDS, 16B per lane; LDS dest = wave-uniform base + lane*16
__device__ __forceinline__ void gll16(const void* g, void* l) {
  __builtin_amdgcn_global_load_lds(
      (const __attribute__((address_space(1))) void*)(uintptr_t)(g),
      (__attribute__((address_space(3))) void*)(uintptr_t)(l), 16, 0, 0);
}

// ---------------------------------------------------------------------------
// Kernel 1: WcatT[c][k] bf16, c in [0,128): cols 0..83 = W_loc, 84..104 = W_score,
// rest zero-padded. Layout [128][4096] (k contiguous for MFMA B-fragments).
// ---------------------------------------------------------------------------
__global__ __launch_bounds__(256) void k_wcat(const float* __restrict__ Wl,
                                              const float* __restrict__ Ws,
                                              unsigned short* __restrict__ WcatT) {
  int idx = blockIdx.x * 256 + threadIdx.x;  // 2048 blocks * 256 = 128*4096
  int c = idx >> 12;
  int k = idx & 4095;
  float v = 0.0f;
  if (c < 84)       v = Wl[k * 84 + c];
  else if (c < 105) v = Ws[k * 21 + (c - 84)];
  WcatT[idx] = f2bf(v);
}

// ---------------------------------------------------------------------------
// Kernel 2: bc[c] = sum_k b_fc[k]*Wcat[k][c] + bias[c]   (c<105; else 0)
// ---------------------------------------------------------------------------
__global__ __launch_bounds__(256) void k_bc(const float* __restrict__ bfc,
                                            const float* __restrict__ Wl,
                                            const float* __restrict__ Ws,
                                            const float* __restrict__ bl,
                                            const float* __restrict__ bs,
                                            float* __restrict__ bc) {
  int c = blockIdx.x;  // 128 blocks
  int t = threadIdx.x;
  __shared__ float red[256];
  float p = 0.0f;
  if (c < 105) {
    for (int k = t; k < 4096; k += 256) {
      float w = (c < 84) ? Wl[k * 84 + c] : Ws[k * 21 + (c - 84)];
      p += bfc[k] * w;
    }
  }
  red[t] = p;
  __syncthreads();
  for (int s = 128; s > 0; s >>= 1) {
    if (t < s) red[t] += red[t + s];
    __syncthreads();
  }
  if (t == 0) {
    float bias = (c < 84) ? bl[c] : (c < 105 ? bs[c - 84] : 0.0f);
    bc[c] = (c < 105) ? (red[0] + bias) : 0.0f;
  }
}

// ---------------------------------------------------------------------------
// Kernel 3: crop_and_resize (tf semantics, bilinear, extrapolation 0) ->
// pool bf16 [2000][25088], row = roi, k = (iy*7+ix)*512 + ch.
// One block per roi; 256 threads x 2 channels; coords are wave-uniform.
// ---------------------------------------------------------------------------
__global__ __launch_bounds__(256) void k_pool(const float* __restrict__ F,
                                              const float* __restrict__ rois,
                                              const int* __restrict__ ihp,
                                              const int* __restrict__ iwp,
                                              unsigned short* __restrict__ A) {
  const int r = blockIdx.x;
  const int t = threadIdx.x;
  const float ih = (float)ihp[0], iw = (float)iwp[0];
  const float y1 = rois[r * 4 + 0] / ih;
  const float x1 = rois[r * 4 + 1] / iw;
  const float y2 = rois[r * 4 + 2] / ih;
  const float x2 = rois[r * 4 + 3] / iw;
  const float sy = (y2 - y1) * 49.0f / 6.0f;   // (H-1)/(ph-1)
  const float sx = (x2 - x1) * 49.0f / 6.0f;
  const int ch = t * 2;
  unsigned int* __restrict__ Arow = (unsigned int*)(A + (size_t)r * KBIG);
  for (int cell = 0; cell < 49; ++cell) {
    const int iy = cell / 7, ix = cell - iy * 7;
    const float in_y = y1 * 49.0f + (float)iy * sy;
    const float in_x = x1 * 49.0f + (float)ix * sx;
    const float y0f = floorf(in_y), x0f = floorf(in_x);
    const float yl = in_y - y0f, xl = in_x - x0f;
    const int y0  = (int)fminf(fmaxf(y0f, 0.0f), 49.0f);
    const int y1i = (int)fminf(fmaxf(y0f + 1.0f, 0.0f), 49.0f);
    const int x0  = (int)fminf(fmaxf(x0f, 0.0f), 49.0f);
    const int x1i = (int)fminf(fmaxf(x0f + 1.0f, 0.0f), 49.0f);
    const bool valid = (in_y >= 0.0f) && (in_y <= 49.0f) &&
                       (in_x >= 0.0f) && (in_x <= 49.0f);
    float2 f00 = *(const float2*)&F[(y0 * 50 + x0) * 512 + ch];
    float2 f01 = *(const float2*)&F[(y0 * 50 + x1i) * 512 + ch];
    float2 f10 = *(const float2*)&F[(y1i * 50 + x0) * 512 + ch];
    float2 f11 = *(const float2*)&F[(y1i * 50 + x1i) * 512 + ch];
    float o0 = 0.0f, o1 = 0.0f;
    if (valid) {
      float t0 = f00.x * (1.0f - xl) + f01.x * xl;
      float t1 = f00.y * (1.0f - xl) + f01.y * xl;
      float b0 = f10.x * (1.0f - xl) + f11.x * xl;
      float b1 = f10.y * (1.0f - xl) + f11.y * xl;
      o0 = t0 * (1.0f - yl) + b0 * yl;
      o1 = t1 * (1.0f - yl) + b1 * yl;
    }
    unsigned int pk = (unsigned int)f2bf(o0) | ((unsigned int)f2bf(o1) << 16);
    Arow[(cell * 512 + ch) >> 1] = pk;
  }
}

// ---------------------------------------------------------------------------
// GEMM common geometry: block tile 64(M) x 128(N), BK=64, 4 waves (2x2),
// wave tile 32x64, mfma_f32_16x16x32_bf16, acc[2][4].
// LDS tiles are [rows][64] bf16 with XOR swizzle: phys = p ^ ((row&7)<<4).
// global_load_lds writes linearly; the SOURCE address is pre-inverse-swizzled
// (jlog), ds_read_b128 applies the same XOR -> conflict-free reads.
// ---------------------------------------------------------------------------

// Kernel 4: WcT[n][m] bf16 = (W_fc @ WcatT^T)^T.  M=25088 (392 tiles), K=4096.
// A = W_fc fp32 (reg-stage + convert + swizzled ds_write), B = WcatT via gll16.
__global__ __launch_bounds__(256) void k_gemm1(const float* __restrict__ Wfc,
                                               const unsigned short* __restrict__ WcatT,
                                               unsigned short* __restrict__ WcT) {
  __shared__ __align__(16) char sA[8192];    // 64 x 64 bf16
  __shared__ __align__(16) char sB[16384];   // 128 x 64 bf16
  const int t = threadIdx.x;
  const int lane = t & 63, wid = t >> 6;
  const int wm = wid >> 1, wn = wid & 1;
  const int l15 = lane & 15, l4 = lane >> 4;
  const int mtile = blockIdx.x * 64;
  const int jlog = (t & 7) ^ ((t >> 3) & 7);
  f32x4 acc[2][4] = {};

  const int arow = t >> 2;        // 0..63
  const int akq  = t & 3;         // 16-float chunk within the 64-col slice
  const float* aptr = Wfc + (size_t)(mtile + arow) * NMID + akq * 16;
  char* awr0 = sA + arow * 128 + ((((akq << 1) + 0) ^ (arow & 7)) << 4);
  char* awr1 = sA + arow * 128 + ((((akq << 1) + 1) ^ (arow & 7)) << 4);

  for (int ks = 0; ks < 64; ++ks) {
    const int k0 = ks * 64;
    f32x4 v0 = *(const f32x4*)(aptr + k0 + 0);
    f32x4 v1 = *(const f32x4*)(aptr + k0 + 4);
    f32x4 v2 = *(const f32x4*)(aptr + k0 + 8);
    f32x4 v3 = *(const f32x4*)(aptr + k0 + 12);
#pragma unroll
    for (int c = 0; c < 4; ++c) {
      const int row = c * 32 + (t >> 3);
      gll16(WcatT + (size_t)row * NMID + k0 + jlog * 8, sB + c * 4096 + wid * 1024);
    }
    u16x8 p0, p1;
#pragma unroll
    for (int i = 0; i < 4; ++i) {
      p0[i]     = f2bf(v0[i]);
      p0[i + 4] = f2bf(v1[i]);
      p1[i]     = f2bf(v2[i]);
      p1[i + 4] = f2bf(v3[i]);
    }
    *(u16x8*)awr0 = p0;
    *(u16x8*)awr1 = p1;
    __syncthreads();
#pragma unroll
    for (int kh = 0; kh < 2; ++kh) {
      bfx8 af[2], bfr[4];
#pragma unroll
      for (int mi = 0; mi < 2; ++mi) {
        const int row = wm * 32 + mi * 16 + l15;
        af[mi] = *(const bfx8*)(sA + row * 128 + ((((kh << 2) + l4) ^ (row & 7)) << 4));
      }
#pragma unroll
      for (int ni = 0; ni < 4; ++ni) {
        const int row = wn * 64 + ni * 16 + l15;
        bfr[ni] = *(const bfx8*)(sB + row * 128 + ((((kh << 2) + l4) ^ (row & 7)) << 4));
      }
#pragma unroll
      for (int mi = 0; mi < 2; ++mi)
#pragma unroll
        for (int ni = 0; ni < 4; ++ni)
          acc[mi][ni] = __builtin_amdgcn_mfma_f32_16x16x32_bf16(af[mi], bfr[ni], acc[mi][ni], 0, 0, 0);
    }
    __syncthreads();
  }
  // D layout: col = lane&15, row = (lane>>4)*4 + i  (m89-verified)
#pragma unroll
  for (int mi = 0; mi < 2; ++mi)
#pragma unroll
    for (int ni = 0; ni < 4; ++ni)
#pragma unroll
      for (int i = 0; i < 4; ++i) {
        const int gm = mtile + wm * 32 + mi * 16 + l4 * 4 + i;
        const int gn = wn * 64 + ni * 16 + l15;
        WcT[(size_t)gn * KBIG + gm] = f2bf(acc[mi][ni][i]);
      }
}

// Kernel 5: partials[bid][64][128] fp32 = pool_tile @ WcT_slice.
// grid = 32 M-tiles * 8 K-splits; split k-range = 3136 (49 BK-steps).
__global__ __launch_bounds__(256) void k_gemm2(const unsigned short* __restrict__ Ap,
                                               const unsigned short* __restrict__ WcT,
                                               float* __restrict__ P) {
  __shared__ __align__(16) char sA[8192];    // 64 x 64 bf16
  __shared__ __align__(16) char sB[16384];   // 128 x 64 bf16
  const int t = threadIdx.x;
  const int lane = t & 63, wid = t >> 6;
  const int wm = wid >> 1, wn = wid & 1;
  const int l15 = lane & 15, l4 = lane >> 4;
  const int bid = blockIdx.x;
  const int mt = bid >> 3, sp = bid & 7;
  const int kbase = sp * 3136;
  const int jlog = (t & 7) ^ ((t >> 3) & 7);
  f32x4 acc[2][4] = {};

  int ar0 = mt * 64 + (t >> 3);
  int ar1 = ar0 + 32;
  if (ar0 > NROIS - 1) ar0 = NROIS - 1;   // clamp: rows >=2000 are dummies
  if (ar1 > NROIS - 1) ar1 = NROIS - 1;
  const unsigned short* asrc0 = Ap + (size_t)ar0 * KBIG + jlog * 8;
  const unsigned short* asrc1 = Ap + (size_t)ar1 * KBIG + jlog * 8;

  for (int ks = 0; ks < 49; ++ks) {
    const int k0 = kbase + ks * 64;
    gll16(asrc0 + k0, sA + wid * 1024);
    gll16(asrc1 + k0, sA + 4096 + wid * 1024);
#pragma unroll
    for (int c = 0; c < 4; ++c) {
      const int row = c * 32 + (t >> 3);
      gll16(WcT + (size_t)row * KBIG + k0 + jlog * 8, sB + c * 4096 + wid * 1024);
    }
    __syncthreads();
#pragma unroll
    for (int kh = 0; kh < 2; ++kh) {
      bfx8 af[2], bfr[4];
#pragma unroll
      for (int mi = 0; mi < 2; ++mi) {
        const int row = wm * 32 + mi * 16 + l15;
        af[mi] = *(const bfx8*)(sA + row * 128 + ((((kh << 2) + l4) ^ (row & 7)) << 4));
      }
#pragma unroll
      for (int ni = 0; ni < 4; ++ni) {
        const int row = wn * 64 + ni * 16 + l15;
        bfr[ni] = *(const bfx8*)(sB + row * 128 + ((((kh << 2) + l4) ^ (row & 7)) << 4));
      }
#pragma unroll
      for (int mi = 0; mi < 2; ++mi)
#pragma unroll
        for (int ni = 0; ni < 4; ++ni)
          acc[mi][ni] = __builtin_amdgcn_mfma_f32_16x16x32_bf16(af[mi], bfr[ni], acc[mi][ni], 0, 0, 0);
    }
    __syncthreads();
  }
  float* out = P + (size_t)bid * 8192;
#pragma unroll
  for (int mi = 0; mi < 2; ++mi)
#pragma unroll
    for (int ni = 0; ni < 4; ++ni)
#pragma unroll
      for (int i = 0; i < 4; ++i)
        out[(wm * 32 + mi * 16 + l4 * 4 + i) * 128 + wn * 64 + ni * 16 + l15] = acc[mi][ni][i];
}

// ---------------------------------------------------------------------------
// Kernel 6: sum the 8 K-split partials, add bias, scatter to the two outputs.
// ---------------------------------------------------------------------------
__global__ __launch_bounds__(128) void k_reduce(const float* __restrict__ P,
                                                const float* __restrict__ bc,
                                                float* __restrict__ out) {
  const int m = blockIdx.x;     // 0..1999
  const int c = threadIdx.x;    // 0..127
  if (c >= 105) return;
  const int mt = m >> 6, r = m & 63;
  float sum = 0.0f;
#pragma unroll
  for (int s = 0; s < 8; ++s)
    sum += P[(size_t)((mt * 8 + s) * 8192) + r * 128 + c];
  sum += bc[c];
  if (c < 84) out[m * 84 + c] = sum;
  else        out[168000 + m * 21 + (c - 84)] = sum;
}

// ---------------------------------------------------------------------------
extern "C" void kernel_launch(void* const* d_in, const int* in_sizes, int n_in,
                              void* d_out, int out_size, void* d_ws, size_t ws_size,
                              hipStream_t stream) {
  const float* F    = (const float*)d_in[0];
  const float* rois = (const float*)d_in[1];
  const int*   ih   = (const int*)d_in[2];
  const int*   iw   = (const int*)d_in[3];
  const float* Wfc  = (const float*)d_in[4];
  const float* bfc  = (const float*)d_in[5];
  const float* Wl   = (const float*)d_in[6];
  const float* bl   = (const float*)d_in[7];
  const float* Ws   = (const float*)d_in[8];
  const float* bs   = (const float*)d_in[9];
  (void)in_sizes; (void)n_in; (void)out_size; (void)ws_size;

  char* ws = (char*)d_ws;
  // ws layout (bytes):
  //   pool bf16 [2000][25088]           @ 0          (100,352,000)
  //   WcatT bf16 [128][4096]            @ 100352000  (1,048,576)
  //   WcT  bf16 [128][25088]            @ 101400576  (6,422,528)
  //   bc   f32  [128]                   @ 107823104  (512)
  //   partials f32 [256][64][128]       @ 107823616  (8,388,608)   total ~110.8 MB
  unsigned short* Apool = (unsigned short*)(ws);
  unsigned short* WcatT = (unsigned short*)(ws + 100352000);
  unsigned short* WcT   = (unsigned short*)(ws + 101400576);
  float*          bc    = (float*)(ws + 107823104);
  float*          P     = (float*)(ws + 107823616);
  float*          out   = (float*)d_out;

  k_wcat  <<<2048, 256, 0, stream>>>(Wl, Ws, WcatT);
  k_bc    <<<128,  256, 0, stream>>>(bfc, Wl, Ws, bl, bs, bc);
  k_pool  <<<2000, 256, 0, stream>>>(F, rois, ih, iw, Apool);
  k_gemm1 <<<392,  256, 0, stream>>>(Wfc, WcatT, WcT);
  k_gemm2 <<<256,  256, 0, stream>>>(Apool, WcT, P);
  k_reduce<<<2000, 128, 0, stream>>>(P, bc, out);
}

// Round 2
// 235.688 us; speedup vs baseline: 1.0934x; 1.0934x over previous
//
#include <hip/hip_runtime.h>
#include <stdint.h>

// ---------------------------------------------------------------------------
// RoIHead: out = crop_and_resize(feature, rois) @ (W_fc @ [W_loc|W_score])
//                + (b_fc @ [W_loc|W_score] + [b_loc|b_score])
// 413 GF -> 32 GF; floor = one 411 MB stream of W_fc (~65us) + ~35us rest.
// R2: occupancy fixes (gemm1 784 blocks, gemm2 896 blocks), pool fused into
// the gemm1 launch so its 100MB write hides under gemm1's 411MB read.
// ---------------------------------------------------------------------------

typedef float          f32x4 __attribute__((ext_vector_type(4)));
typedef __bf16         bfx8  __attribute__((ext_vector_type(8)));
typedef unsigned short u16x8 __attribute__((ext_vector_type(8)));
typedef unsigned short u16x4 __attribute__((ext_vector_type(4)));

#define KBIG 25088   // 7*7*512
#define NMID 4096    // FC_OUT
#define NROIS 2000
#define G1BLOCKS 784 // 25088/32
#define SPLITS 28    // gemm2 K-splits (392 BK steps = 28*14)

__device__ __forceinline__ unsigned short f2bf(float f) {
  unsigned int u = __float_as_uint(f);
  return (unsigned short)((u + 0x7fffu + ((u >> 16) & 1u)) >> 16);
}

__device__ __forceinline__ void gll16(const void* g, void* l) {
  __builtin_amdgcn_global_load_lds(
      (const __attribute__((address_space(1))) void*)(uintptr_t)(g),
      (__attribute__((address_space(3))) void*)(uintptr_t)(l), 16, 0, 0);
}

// ---------------------------------------------------------------------------
// prep: blocks 0..2047 build WcatT[128][4096] bf16 (zero-padded cols>=105);
//       blocks 2048..2175 compute bc[c] = b_fc . Wcat[:,c] + bias[c].
// ---------------------------------------------------------------------------
__global__ __launch_bounds__(256) void k_prep(const float* __restrict__ Wl,
                                              const float* __restrict__ Ws,
                                              const float* __restrict__ bfc,
                                              const float* __restrict__ bl,
                                              const float* __restrict__ bs,
                                              unsigned short* __restrict__ WcatT,
                                              float* __restrict__ bc) {
  if (blockIdx.x < 2048) {
    int idx = blockIdx.x * 256 + threadIdx.x;
    int c = idx >> 12, k = idx & 4095;
    float v = 0.0f;
    if (c < 84)       v = Wl[k * 84 + c];
    else if (c < 105) v = Ws[k * 21 + (c - 84)];
    WcatT[idx] = f2bf(v);
  } else {
    int c = blockIdx.x - 2048;   // 0..127
    int t = threadIdx.x;
    __shared__ float red[256];
    float p = 0.0f;
    if (c < 105) {
      for (int k = t; k < 4096; k += 256) {
        float w = (c < 84) ? Wl[k * 84 + c] : Ws[k * 21 + (c - 84)];
        p += bfc[k] * w;
      }
    }
    red[t] = p;
    __syncthreads();
    for (int s = 128; s > 0; s >>= 1) {
      if (t < s) red[t] += red[t + s];
      __syncthreads();
    }
    if (t == 0) {
      float bias = (c < 84) ? bl[c] : (c < 105 ? bs[c - 84] : 0.0f);
      bc[c] = (c < 105) ? (red[0] + bias) : 0.0f;
    }
  }
}

// ---------------------------------------------------------------------------
// Fused launch: blocks [0,784) = GEMM1 tile (BM=32), blocks [784,2784) = pool.
// GEMM1: WcT[n][m] bf16 = (W_fc @ WcatT^T)^T.  M=25088, N=128, K=4096.
//   4 waves, wave tile 32(M)x32(N), BK=64, mfma 16x16x32 bf16.
//   LDS XOR swizzle: phys_chunk = logical_chunk ^ (row&7)  (16B chunks).
//   A fp32 reg-staged (load->cvt->swizzled ds_write); B via global_load_lds
//   with inverse-swizzled source (jlog).
// Pool: tf crop_and_resize (bilinear, extrap 0) -> bf16 [2000][25088].
// ---------------------------------------------------------------------------
__global__ __launch_bounds__(256) void k_pool_gemm1(
    const float* __restrict__ F, const float* __restrict__ rois,
    const int* __restrict__ ihp, const int* __restrict__ iwp,
    unsigned short* __restrict__ A,
    const float* __restrict__ Wfc, const unsigned short* __restrict__ WcatT,
    unsigned short* __restrict__ WcT) {
  const int t = threadIdx.x;
  if (blockIdx.x < G1BLOCKS) {
    // ---------------- GEMM1 ----------------
    __shared__ __align__(16) char sA[4096];    // 32 x 64 bf16, swizzled
    __shared__ __align__(16) char sB[16384];   // 128 x 64 bf16, swizzled
    const int lane = t & 63, wid = t >> 6;
    const int l15 = lane & 15, l4 = lane >> 4;
    const int mtile = blockIdx.x * 32;
    const int jlog = (t & 7) ^ ((t >> 3) & 7);
    f32x4 acc[2][2] = {};

    const int arow = t >> 3;     // 0..31
    const int aj = t & 7;        // 8-float logical chunk
    const float* aptr = Wfc + (size_t)(mtile + arow) * NMID + aj * 8;
    char* awr = sA + arow * 128 + ((aj ^ (arow & 7)) << 4);

    f32x4 v0 = *(const f32x4*)(aptr);
    f32x4 v1 = *(const f32x4*)(aptr + 4);
    for (int ks = 0; ks < 64; ++ks) {
      u16x8 p;
#pragma unroll
      for (int i = 0; i < 4; ++i) { p[i] = f2bf(v0[i]); p[i + 4] = f2bf(v1[i]); }
      *(u16x8*)awr = p;
#pragma unroll
      for (int c = 0; c < 4; ++c)
        gll16(WcatT + (size_t)(c * 32 + (t >> 3)) * NMID + ks * 64 + jlog * 8,
              sB + c * 4096 + wid * 1024);
      __syncthreads();
      if (ks < 63) {
        v0 = *(const f32x4*)(aptr + (ks + 1) * 64);
        v1 = *(const f32x4*)(aptr + (ks + 1) * 64 + 4);
      }
#pragma unroll
      for (int kh = 0; kh < 2; ++kh) {
        bfx8 af[2], bfr[2];
#pragma unroll
        for (int mi = 0; mi < 2; ++mi) {
          const int row = mi * 16 + l15;
          af[mi] = *(const bfx8*)(sA + row * 128 + ((((kh << 2) + l4) ^ (row & 7)) << 4));
        }
#pragma unroll
        for (int ni = 0; ni < 2; ++ni) {
          const int row = wid * 32 + ni * 16 + l15;
          bfr[ni] = *(const bfx8*)(sB + row * 128 + ((((kh << 2) + l4) ^ (row & 7)) << 4));
        }
#pragma unroll
        for (int mi = 0; mi < 2; ++mi)
#pragma unroll
          for (int ni = 0; ni < 2; ++ni)
            acc[mi][ni] = __builtin_amdgcn_mfma_f32_16x16x32_bf16(af[mi], bfr[ni], acc[mi][ni], 0, 0, 0);
      }
      __syncthreads();
    }
    // D layout: col = lane&15, row = (lane>>4)*4 + i -> 4 consecutive m = 8B store
#pragma unroll
    for (int mi = 0; mi < 2; ++mi)
#pragma unroll
      for (int ni = 0; ni < 2; ++ni) {
        const int gm0 = mtile + mi * 16 + l4 * 4;
        const int gn = wid * 32 + ni * 16 + l15;
        u16x4 pk;
#pragma unroll
        for (int i = 0; i < 4; ++i) pk[i] = f2bf(acc[mi][ni][i]);
        *(u16x4*)(WcT + (size_t)gn * KBIG + gm0) = pk;
      }
  } else {
    // ---------------- pool ----------------
    const int r = blockIdx.x - G1BLOCKS;
    const float ih = (float)ihp[0], iw = (float)iwp[0];
    const float y1 = rois[r * 4 + 0] / ih;
    const float x1 = rois[r * 4 + 1] / iw;
    const float y2 = rois[r * 4 + 2] / ih;
    const float x2 = rois[r * 4 + 3] / iw;
    const float sy = (y2 - y1) * 49.0f / 6.0f;
    const float sx = (x2 - x1) * 49.0f / 6.0f;
    const int ch = t * 2;
    unsigned int* __restrict__ Arow = (unsigned int*)(A + (size_t)r * KBIG);
    for (int cell = 0; cell < 49; ++cell) {
      const int iy = cell / 7, ix = cell - iy * 7;
      const float in_y = y1 * 49.0f + (float)iy * sy;
      const float in_x = x1 * 49.0f + (float)ix * sx;
      const float y0f = floorf(in_y), x0f = floorf(in_x);
      const float yl = in_y - y0f, xl = in_x - x0f;
      const int y0  = (int)fminf(fmaxf(y0f, 0.0f), 49.0f);
      const int y1i = (int)fminf(fmaxf(y0f + 1.0f, 0.0f), 49.0f);
      const int x0  = (int)fminf(fmaxf(x0f, 0.0f), 49.0f);
      const int x1i = (int)fminf(fmaxf(x0f + 1.0f, 0.0f), 49.0f);
      const bool valid = (in_y >= 0.0f) && (in_y <= 49.0f) &&
                         (in_x >= 0.0f) && (in_x <= 49.0f);
      float2 f00 = *(const float2*)&F[(y0 * 50 + x0) * 512 + ch];
      float2 f01 = *(const float2*)&F[(y0 * 50 + x1i) * 512 + ch];
      float2 f10 = *(const float2*)&F[(y1i * 50 + x0) * 512 + ch];
      float2 f11 = *(const float2*)&F[(y1i * 50 + x1i) * 512 + ch];
      float o0 = 0.0f, o1 = 0.0f;
      if (valid) {
        float t0 = f00.x * (1.0f - xl) + f01.x * xl;
        float t1 = f00.y * (1.0f - xl) + f01.y * xl;
        float b0 = f10.x * (1.0f - xl) + f11.x * xl;
        float b1 = f10.y * (1.0f - xl) + f11.y * xl;
        o0 = t0 * (1.0f - yl) + b0 * yl;
        o1 = t1 * (1.0f - yl) + b1 * yl;
      }
      Arow[(cell * 512 + ch) >> 1] =
          (unsigned int)f2bf(o0) | ((unsigned int)f2bf(o1) << 16);
    }
  }
}

// ---------------------------------------------------------------------------
// GEMM2: partials[mt*28+sp][64][128] fp32 = pool_tile(mt) @ WcT_slice(sp).
// grid (32 mt, 28 sp); mt fastest so same-sp blocks share the 229KB B slice.
// Block tile 64x128, BK=64, 14 steps, 4 waves (2Mx2N), wave tile 32x64.
// ---------------------------------------------------------------------------
__global__ __launch_bounds__(256) void k_gemm2(const unsigned short* __restrict__ Ap,
                                               const unsigned short* __restrict__ WcT,
                                               float* __restrict__ P) {
  __shared__ __align__(16) char sA[8192];    // 64 x 64 bf16
  __shared__ __align__(16) char sB[16384];   // 128 x 64 bf16
  const int t = threadIdx.x;
  const int lane = t & 63, wid = t >> 6;
  const int wm = wid >> 1, wn = wid & 1;
  const int l15 = lane & 15, l4 = lane >> 4;
  const int mt = blockIdx.x, sp = blockIdx.y;
  const int kbase = sp * 896;     // 14 BK-steps of 64
  const int jlog = (t & 7) ^ ((t >> 3) & 7);
  f32x4 acc[2][4] = {};

  int ar0 = mt * 64 + (t >> 3);
  int ar1 = ar0 + 32;
  if (ar0 > NROIS - 1) ar0 = NROIS - 1;
  if (ar1 > NROIS - 1) ar1 = NROIS - 1;
  const unsigned short* asrc0 = Ap + (size_t)ar0 * KBIG + jlog * 8;
  const unsigned short* asrc1 = Ap + (size_t)ar1 * KBIG + jlog * 8;

  for (int ks = 0; ks < 14; ++ks) {
    const int k0 = kbase + ks * 64;
    gll16(asrc0 + k0, sA + wid * 1024);
    gll16(asrc1 + k0, sA + 4096 + wid * 1024);
#pragma unroll
    for (int c = 0; c < 4; ++c)
      gll16(WcT + (size_t)(c * 32 + (t >> 3)) * KBIG + k0 + jlog * 8,
            sB + c * 4096 + wid * 1024);
    __syncthreads();
#pragma unroll
    for (int kh = 0; kh < 2; ++kh) {
      bfx8 af[2], bfr[4];
#pragma unroll
      for (int mi = 0; mi < 2; ++mi) {
        const int row = wm * 32 + mi * 16 + l15;
        af[mi] = *(const bfx8*)(sA + row * 128 + ((((kh << 2) + l4) ^ (row & 7)) << 4));
      }
#pragma unroll
      for (int ni = 0; ni < 4; ++ni) {
        const int row = wn * 64 + ni * 16 + l15;
        bfr[ni] = *(const bfx8*)(sB + row * 128 + ((((kh << 2) + l4) ^ (row & 7)) << 4));
      }
#pragma unroll
      for (int mi = 0; mi < 2; ++mi)
#pragma unroll
        for (int ni = 0; ni < 4; ++ni)
          acc[mi][ni] = __builtin_amdgcn_mfma_f32_16x16x32_bf16(af[mi], bfr[ni], acc[mi][ni], 0, 0, 0);
    }
    __syncthreads();
  }
  float* out = P + (size_t)(mt * SPLITS + sp) * 8192;
#pragma unroll
  for (int mi = 0; mi < 2; ++mi)
#pragma unroll
    for (int ni = 0; ni < 4; ++ni)
#pragma unroll
      for (int i = 0; i < 4; ++i)
        out[(wm * 32 + mi * 16 + l4 * 4 + i) * 128 + wn * 64 + ni * 16 + l15] = acc[mi][ni][i];
}

// ---------------------------------------------------------------------------
// reduce: sum 28 K-split partials + bias, scatter into the two outputs.
// ---------------------------------------------------------------------------
__global__ __launch_bounds__(128) void k_reduce(const float* __restrict__ P,
                                                const float* __restrict__ bc,
                                                float* __restrict__ out) {
  const int m = blockIdx.x;     // 0..1999
  const int c = threadIdx.x;    // 0..127
  if (c >= 105) return;
  const int mt = m >> 6, r = m & 63;
  float sum = 0.0f;
#pragma unroll
  for (int s = 0; s < SPLITS; ++s)
    sum += P[(size_t)(mt * SPLITS + s) * 8192 + r * 128 + c];
  sum += bc[c];
  if (c < 84) out[m * 84 + c] = sum;
  else        out[168000 + m * 21 + (c - 84)] = sum;
}

// ---------------------------------------------------------------------------
extern "C" void kernel_launch(void* const* d_in, const int* in_sizes, int n_in,
                              void* d_out, int out_size, void* d_ws, size_t ws_size,
                              hipStream_t stream) {
  const float* F    = (const float*)d_in[0];
  const float* rois = (const float*)d_in[1];
  const int*   ih   = (const int*)d_in[2];
  const int*   iw   = (const int*)d_in[3];
  const float* Wfc  = (const float*)d_in[4];
  const float* bfc  = (const float*)d_in[5];
  const float* Wl   = (const float*)d_in[6];
  const float* bl   = (const float*)d_in[7];
  const float* Ws   = (const float*)d_in[8];
  const float* bs   = (const float*)d_in[9];
  (void)in_sizes; (void)n_in; (void)out_size; (void)ws_size;

  char* ws = (char*)d_ws;
  // ws layout (bytes):
  //   pool  bf16 [2000][25088]      @ 0          (100,352,000)
  //   WcatT bf16 [128][4096]        @ 100352000  (1,048,576)
  //   WcT   bf16 [128][25088]       @ 101400576  (6,422,528)
  //   bc    f32  [128]              @ 107823104  (512)
  //   P     f32  [896][64][128]     @ 107823616  (29,360,128)  total ~137.2 MB
  unsigned short* Apool = (unsigned short*)(ws);
  unsigned short* WcatT = (unsigned short*)(ws + 100352000);
  unsigned short* WcT   = (unsigned short*)(ws + 101400576);
  float*          bc    = (float*)(ws + 107823104);
  float*          P     = (float*)(ws + 107823616);
  float*          out   = (float*)d_out;

  k_prep      <<<2176, 256, 0, stream>>>(Wl, Ws, bfc, bl, bs, WcatT, bc);
  k_pool_gemm1<<<G1BLOCKS + NROIS, 256, 0, stream>>>(F, rois, ih, iw, Apool,
                                                     Wfc, WcatT, WcT);
  k_gemm2     <<<dim3(32, SPLITS), 256, 0, stream>>>(Apool, WcT, P);
  k_reduce    <<<NROIS, 128, 0, stream>>>(P, bc, out);
}

// Round 4
// 232.891 us; speedup vs baseline: 1.1065x; 1.0120x over previous
//
#include <hip/hip_runtime.h>
#include <stdint.h>

// ---------------------------------------------------------------------------
// RoIHead: out = crop_and_resize(feature, rois) @ (W_fc @ [W_loc|W_score])
//                + (b_fc @ [W_loc|W_score] + [b_loc|b_score])
// 413 GF -> 32 GF. Floor: 411 MB W_fc + 100 MB pool = ~81 us HBM.
// R4: fix R3's race — counted vmcnt(12) in gemm1 requires stageB-before-loadA
// issue order; pin it with sched_barrier(0) (LLVM reorders VMEM ops within a
// region, breaking the ledger; gemm2's one-group-per-region count was robust).
// ---------------------------------------------------------------------------

typedef float          f32x4 __attribute__((ext_vector_type(4)));
typedef __bf16         bfx8  __attribute__((ext_vector_type(8)));
typedef unsigned short u16x8 __attribute__((ext_vector_type(8)));

#define KBIG 25088   // 7*7*512
#define NMID 4096    // FC_OUT
#define NROIS 2000
#define G1BLOCKS 784 // 392 m-tiles x 2 k-splits
#define SPLITS 28    // gemm2 K-splits (392 BK steps = 28*14)

__device__ __forceinline__ unsigned short f2bf(float f) {
  unsigned int u = __float_as_uint(f);
  return (unsigned short)((u + 0x7fffu + ((u >> 16) & 1u)) >> 16);
}

__device__ __forceinline__ void gll16(const void* g, void* l) {
  __builtin_amdgcn_global_load_lds(
      (const __attribute__((address_space(1))) void*)(uintptr_t)(g),
      (__attribute__((address_space(3))) void*)(uintptr_t)(l), 16, 0, 0);
}

// ---------------------------------------------------------------------------
// prep: blocks 0..2047 build WcatT[128][4096] bf16 (zero-padded cols>=105);
//       blocks 2048..2175 compute bc[c] = b_fc . Wcat[:,c] + bias[c].
// ---------------------------------------------------------------------------
__global__ __launch_bounds__(256) void k_prep(const float* __restrict__ Wl,
                                              const float* __restrict__ Ws,
                                              const float* __restrict__ bfc,
                                              const float* __restrict__ bl,
                                              const float* __restrict__ bs,
                                              unsigned short* __restrict__ WcatT,
                                              float* __restrict__ bc) {
  if (blockIdx.x < 2048) {
    int idx = blockIdx.x * 256 + threadIdx.x;
    int c = idx >> 12, k = idx & 4095;
    float v = 0.0f;
    if (c < 84)       v = Wl[k * 84 + c];
    else if (c < 105) v = Ws[k * 21 + (c - 84)];
    WcatT[idx] = f2bf(v);
  } else {
    int c = blockIdx.x - 2048;   // 0..127
    int t = threadIdx.x;
    __shared__ float red[256];
    float p = 0.0f;
    if (c < 105) {
      for (int k = t; k < 4096; k += 256) {
        float w = (c < 84) ? Wl[k * 84 + c] : Ws[k * 21 + (c - 84)];
        p += bfc[k] * w;
      }
    }
    red[t] = p;
    __syncthreads();
    for (int s = 128; s > 0; s >>= 1) {
      if (t < s) red[t] += red[t + s];
      __syncthreads();
    }
    if (t == 0) {
      float bias = (c < 84) ? bl[c] : (c < 105 ? bs[c - 84] : 0.0f);
      bc[c] = (c < 105) ? (red[0] + bias) : 0.0f;
    }
  }
}

// ---------------------------------------------------------------------------
// Fused: blocks [0,784) = GEMM1 (mt = bx>>1, ksplit = bx&1), [784,2784) = pool.
// GEMM1: Pg1[sp][n][m] f32 partial of (W_fc @ WcatT^T)^T.
//   A: direct global->reg fp32, 2-chunk prefetch; B: LDS dbuf, gll16 with
//   pre-inverse-swizzled source; raw s_barrier + counted vmcnt(12).
//   Ledger (pinned order B(c) < A(c+1) < B(c+1) < A(c+2)): at the wait,
//   outstanding after cvtA = B(c)4 A(c+1)4 B(c+1)4 A(c+2)4 = 16; vmcnt(12)
//   retires exactly B(c). sched_barrier(0) pins stageB before loadA.
// ---------------------------------------------------------------------------
__global__ __launch_bounds__(256, 3) void k_pool_gemm1(
    const float* __restrict__ F, const float* __restrict__ rois,
    const int* __restrict__ ihp, const int* __restrict__ iwp,
    unsigned short* __restrict__ A,
    const float* __restrict__ Wfc, const unsigned short* __restrict__ WcatT,
    float* __restrict__ Pg1) {
  const int t = threadIdx.x;
  __shared__ __align__(16) char sB[32768];   // [2][128 rows][128 B]
  if (blockIdx.x < G1BLOCKS) {
    // ---------------- GEMM1 ----------------
    const int lane = t & 63, wid = t >> 6;
    const int l15 = lane & 15, l4 = lane >> 4;
    const int mt = blockIdx.x >> 1, sp = blockIdx.x & 1;
    const int m0 = mt * 64;
    const int kbase = sp * 2048;
    const int jlog = (t & 7) ^ ((t >> 3) & 7);
    f32x4 acc[8] = {};
    f32x4 rA[4], rB[4];

    const float* aptr = Wfc + (size_t)(m0 + wid * 16 + l15) * NMID + kbase + l4 * 8;

    auto stageB = [&](int c, int off) {
#pragma unroll
      for (int q = 0; q < 4; ++q)
        gll16(WcatT + (size_t)(q * 32 + (t >> 3)) * NMID + kbase + c * 64 + jlog * 8,
              sB + off + q * 4096 + wid * 1024);
    };
    auto loadA = [&](f32x4* dst, int c) {
      dst[0] = *(const f32x4*)(aptr + c * 64);
      dst[1] = *(const f32x4*)(aptr + c * 64 + 4);
      dst[2] = *(const f32x4*)(aptr + c * 64 + 32);
      dst[3] = *(const f32x4*)(aptr + c * 64 + 36);
    };
    auto cvtA = [&](bfx8& af0, bfx8& af1, const f32x4* r) {
      u16x8 p0, p1;
#pragma unroll
      for (int i = 0; i < 4; ++i) {
        p0[i] = f2bf(r[0][i]); p0[i + 4] = f2bf(r[1][i]);
        p1[i] = f2bf(r[2][i]); p1[i + 4] = f2bf(r[3][i]);
      }
      af0 = *(bfx8*)&p0; af1 = *(bfx8*)&p1;
    };
    auto compute = [&](int off, bfx8 af0, bfx8 af1) {
#pragma unroll
      for (int kk = 0; kk < 2; ++kk) {
        bfx8 bfr[8];
#pragma unroll
        for (int nt = 0; nt < 8; ++nt) {
          const int row = nt * 16 + l15;
          bfr[nt] = *(const bfx8*)(sB + off + row * 128 + ((((kk << 2) + l4) ^ (row & 7)) << 4));
        }
        const bfx8 af = kk ? af1 : af0;
#pragma unroll
        for (int nt = 0; nt < 8; ++nt)
          acc[nt] = __builtin_amdgcn_mfma_f32_16x16x32_bf16(af, bfr[nt], acc[nt], 0, 0, 0);
      }
    };

    // prologue (pinned: B(0) oldest so cc=0's cvt auto-wait also drains B(0))
    stageB(0, 0);
    __builtin_amdgcn_sched_barrier(0);
    loadA(rA, 0);
    loadA(rB, 1);
    for (int cc = 0; cc < 16; ++cc) {
      const int c0 = cc * 2;
      bfx8 af0, af1;
      // even chunk c0 (buf 0)
      cvtA(af0, af1, rA);
      stageB(c0 + 1, 16384);
      __builtin_amdgcn_sched_barrier(0);      // pin: stageB before loadA
      loadA(rA, (c0 + 2 < 32) ? c0 + 2 : 31);
      asm volatile("s_waitcnt vmcnt(12)" ::: "memory");
      __builtin_amdgcn_s_barrier();
      __builtin_amdgcn_sched_barrier(0);
      compute(0, af0, af1);
      __builtin_amdgcn_s_barrier();
      // odd chunk c0+1 (buf 1)
      cvtA(af0, af1, rB);
      stageB((c0 + 2 < 32) ? c0 + 2 : 31, 0);
      __builtin_amdgcn_sched_barrier(0);      // pin: stageB before loadA
      loadA(rB, (c0 + 3 < 32) ? c0 + 3 : 31);
      asm volatile("s_waitcnt vmcnt(12)" ::: "memory");
      __builtin_amdgcn_s_barrier();
      __builtin_amdgcn_sched_barrier(0);
      compute(16384, af0, af1);
      __builtin_amdgcn_s_barrier();
    }
    asm volatile("s_waitcnt vmcnt(0)" ::: "memory");
    // epilogue: D col(lane&15)=n, row((lane>>4)*4+i)=m -> 16B f32 stores
#pragma unroll
    for (int nt = 0; nt < 8; ++nt) {
      const int n = nt * 16 + l15;
      float* dst = Pg1 + ((size_t)sp * 128 + n) * KBIG + m0 + wid * 16 + l4 * 4;
      *(f32x4*)dst = acc[nt];
    }
  } else {
    // ---------------- pool ----------------
    const int r = blockIdx.x - G1BLOCKS;
    const float ih = (float)ihp[0], iw = (float)iwp[0];
    const float y1 = rois[r * 4 + 0] / ih;
    const float x1 = rois[r * 4 + 1] / iw;
    const float y2 = rois[r * 4 + 2] / ih;
    const float x2 = rois[r * 4 + 3] / iw;
    const float sy = (y2 - y1) * 49.0f / 6.0f;
    const float sx = (x2 - x1) * 49.0f / 6.0f;
    const int ch = t * 2;
    unsigned int* __restrict__ Arow = (unsigned int*)(A + (size_t)r * KBIG);
    for (int cell = 0; cell < 49; ++cell) {
      const int iy = cell / 7, ix = cell - iy * 7;
      const float in_y = y1 * 49.0f + (float)iy * sy;
      const float in_x = x1 * 49.0f + (float)ix * sx;
      const float y0f = floorf(in_y), x0f = floorf(in_x);
      const float yl = in_y - y0f, xl = in_x - x0f;
      const int y0  = (int)fminf(fmaxf(y0f, 0.0f), 49.0f);
      const int y1i = (int)fminf(fmaxf(y0f + 1.0f, 0.0f), 49.0f);
      const int x0  = (int)fminf(fmaxf(x0f, 0.0f), 49.0f);
      const int x1i = (int)fminf(fmaxf(x0f + 1.0f, 0.0f), 49.0f);
      const bool valid = (in_y >= 0.0f) && (in_y <= 49.0f) &&
                         (in_x >= 0.0f) && (in_x <= 49.0f);
      float2 f00 = *(const float2*)&F[(y0 * 50 + x0) * 512 + ch];
      float2 f01 = *(const float2*)&F[(y0 * 50 + x1i) * 512 + ch];
      float2 f10 = *(const float2*)&F[(y1i * 50 + x0) * 512 + ch];
      float2 f11 = *(const float2*)&F[(y1i * 50 + x1i) * 512 + ch];
      float o0 = 0.0f, o1 = 0.0f;
      if (valid) {
        float t0 = f00.x * (1.0f - xl) + f01.x * xl;
        float t1 = f00.y * (1.0f - xl) + f01.y * xl;
        float b0 = f10.x * (1.0f - xl) + f11.x * xl;
        float b1 = f10.y * (1.0f - xl) + f11.y * xl;
        o0 = t0 * (1.0f - yl) + b0 * yl;
        o1 = t1 * (1.0f - yl) + b1 * yl;
      }
      Arow[(cell * 512 + ch) >> 1] =
          (unsigned int)f2bf(o0) | ((unsigned int)f2bf(o1) << 16);
    }
  }
}

// ---------------------------------------------------------------------------
// addcvt: WcT[n][m] bf16 = Pg1[0][n][m] + Pg1[1][n][m]
// ---------------------------------------------------------------------------
__global__ __launch_bounds__(256) void k_addcvt(const float* __restrict__ Pg1,
                                                unsigned short* __restrict__ WcT) {
  const size_t i = ((size_t)blockIdx.x * 256 + threadIdx.x) * 8;  // < 128*25088
  f32x4 a0 = *(const f32x4*)(Pg1 + i);
  f32x4 a1 = *(const f32x4*)(Pg1 + i + 4);
  f32x4 b0 = *(const f32x4*)(Pg1 + 3211264 + i);
  f32x4 b1 = *(const f32x4*)(Pg1 + 3211264 + i + 4);
  u16x8 o;
#pragma unroll
  for (int j = 0; j < 4; ++j) {
    o[j]     = f2bf(a0[j] + b0[j]);
    o[j + 4] = f2bf(a1[j] + b1[j]);
  }
  *(u16x8*)(WcT + i) = o;
}

// ---------------------------------------------------------------------------
// GEMM2: P[mt*28+sp][64][128] f32 = pool_tile(mt) @ WcT_slice(sp).
// Counted-vmcnt double buffer: stage(c+1); vmcnt(6); barrier; compute(c);
// barrier. One 6-op staging group per region -> count is order-robust.
// ---------------------------------------------------------------------------
__global__ __launch_bounds__(256) void k_gemm2(const unsigned short* __restrict__ Ap,
                                               const unsigned short* __restrict__ WcT,
                                               float* __restrict__ P) {
  __shared__ __align__(16) char S[49152];
  const int t = threadIdx.x;
  const int lane = t & 63, wid = t >> 6;
  const int wm = wid >> 1, wn = wid & 1;
  const int l15 = lane & 15, l4 = lane >> 4;
  const int mt = blockIdx.x, sp = blockIdx.y;
  const int kbase = sp * 896;     // 14 BK-steps of 64
  const int jlog = (t & 7) ^ ((t >> 3) & 7);
  f32x4 acc[2][4] = {};

  int ar0 = mt * 64 + (t >> 3);
  int ar1 = ar0 + 32;
  if (ar0 > NROIS - 1) ar0 = NROIS - 1;
  if (ar1 > NROIS - 1) ar1 = NROIS - 1;
  const unsigned short* asrc0 = Ap + (size_t)ar0 * KBIG + jlog * 8;
  const unsigned short* asrc1 = Ap + (size_t)ar1 * KBIG + jlog * 8;

  auto stage2 = [&](int c, int off) {
    const int k0 = kbase + c * 64;
    gll16(asrc0 + k0, S + off + wid * 1024);
    gll16(asrc1 + k0, S + off + 4096 + wid * 1024);
#pragma unroll
    for (int q = 0; q < 4; ++q)
      gll16(WcT + (size_t)(q * 32 + (t >> 3)) * KBIG + k0 + jlog * 8,
            S + off + 8192 + q * 4096 + wid * 1024);
  };
  auto compute2 = [&](int off) {
#pragma unroll
    for (int kh = 0; kh < 2; ++kh) {
      bfx8 af[2], bfr[4];
#pragma unroll
      for (int mi = 0; mi < 2; ++mi) {
        const int row = wm * 32 + mi * 16 + l15;
        af[mi] = *(const bfx8*)(S + off + row * 128 + ((((kh << 2) + l4) ^ (row & 7)) << 4));
      }
#pragma unroll
      for (int ni = 0; ni < 4; ++ni) {
        const int row = wn * 64 + ni * 16 + l15;
        bfr[ni] = *(const bfx8*)(S + off + 8192 + row * 128 + ((((kh << 2) + l4) ^ (row & 7)) << 4));
      }
#pragma unroll
      for (int mi = 0; mi < 2; ++mi)
#pragma unroll
        for (int ni = 0; ni < 4; ++ni)
          acc[mi][ni] = __builtin_amdgcn_mfma_f32_16x16x32_bf16(af[mi], bfr[ni], acc[mi][ni], 0, 0, 0);
    }
  };

  stage2(0, 0);
  for (int cc = 0; cc < 7; ++cc) {
    const int c0 = cc * 2;
    stage2(c0 + 1, 24576);
    asm volatile("s_waitcnt vmcnt(6)" ::: "memory");
    __builtin_amdgcn_s_barrier();
    __builtin_amdgcn_sched_barrier(0);
    compute2(0);
    __builtin_amdgcn_s_barrier();
    stage2((c0 + 2 < 14) ? c0 + 2 : 13, 0);
    asm volatile("s_waitcnt vmcnt(6)" ::: "memory");
    __builtin_amdgcn_s_barrier();
    __builtin_amdgcn_sched_barrier(0);
    compute2(24576);
    __builtin_amdgcn_s_barrier();
  }
  asm volatile("s_waitcnt vmcnt(0)" ::: "memory");
  float* out = P + (size_t)(mt * SPLITS + sp) * 8192;
#pragma unroll
  for (int mi = 0; mi < 2; ++mi)
#pragma unroll
    for (int ni = 0; ni < 4; ++ni)
#pragma unroll
      for (int i = 0; i < 4; ++i)
        out[(wm * 32 + mi * 16 + l4 * 4 + i) * 128 + wn * 64 + ni * 16 + l15] = acc[mi][ni][i];
}

// ---------------------------------------------------------------------------
// reduce: sum 28 K-split partials + bias, scatter into the two outputs.
// ---------------------------------------------------------------------------
__global__ __launch_bounds__(128) void k_reduce(const float* __restrict__ P,
                                                const float* __restrict__ bc,
                                                float* __restrict__ out) {
  const int m = blockIdx.x;     // 0..1999
  const int c = threadIdx.x;    // 0..127
  if (c >= 105) return;
  const int mt = m >> 6, r = m & 63;
  float sum = 0.0f;
#pragma unroll
  for (int s = 0; s < SPLITS; ++s)
    sum += P[(size_t)(mt * SPLITS + s) * 8192 + r * 128 + c];
  sum += bc[c];
  if (c < 84) out[m * 84 + c] = sum;
  else        out[168000 + m * 21 + (c - 84)] = sum;
}

// ---------------------------------------------------------------------------
extern "C" void kernel_launch(void* const* d_in, const int* in_sizes, int n_in,
                              void* d_out, int out_size, void* d_ws, size_t ws_size,
                              hipStream_t stream) {
  const float* F    = (const float*)d_in[0];
  const float* rois = (const float*)d_in[1];
  const int*   ih   = (const int*)d_in[2];
  const int*   iw   = (const int*)d_in[3];
  const float* Wfc  = (const float*)d_in[4];
  const float* bfc  = (const float*)d_in[5];
  const float* Wl   = (const float*)d_in[6];
  const float* bl   = (const float*)d_in[7];
  const float* Ws   = (const float*)d_in[8];
  const float* bs   = (const float*)d_in[9];
  (void)in_sizes; (void)n_in; (void)out_size; (void)ws_size;

  char* ws = (char*)d_ws;
  // ws layout (bytes):
  //   pool  bf16 [2000][25088]      @ 0          (100,352,000)
  //   WcatT bf16 [128][4096]        @ 100352000  (1,048,576)
  //   WcT   bf16 [128][25088]       @ 101400576  (6,422,528)
  //   bc    f32  [128]              @ 107823104  (512)
  //   P     f32  [896][64][128]     @ 107823616  (29,360,128)
  //   Pg1   f32  [2][128][25088]    @ 137183744  (25,690,112)  total ~163 MB
  unsigned short* Apool = (unsigned short*)(ws);
  unsigned short* WcatT = (unsigned short*)(ws + 100352000);
  unsigned short* WcT   = (unsigned short*)(ws + 101400576);
  float*          bc    = (float*)(ws + 107823104);
  float*          P     = (float*)(ws + 107823616);
  float*          Pg1   = (float*)(ws + 137183744);
  float*          out   = (float*)d_out;

  k_prep      <<<2176, 256, 0, stream>>>(Wl, Ws, bfc, bl, bs, WcatT, bc);
  k_pool_gemm1<<<G1BLOCKS + NROIS, 256, 0, stream>>>(F, rois, ih, iw, Apool,
                                                     Wfc, WcatT, Pg1);
  k_addcvt    <<<1568, 256, 0, stream>>>(Pg1, WcT);
  k_gemm2     <<<dim3(32, SPLITS), 256, 0, stream>>>(Apool, WcT, P);
  k_reduce    <<<NROIS, 128, 0, stream>>>(P, bc, out);
}

// Round 5
// 220.533 us; speedup vs baseline: 1.1685x; 1.0560x over previous
//
#include <hip/hip_runtime.h>
#include <stdint.h>

// ---------------------------------------------------------------------------
// RoIHead: out = crop_and_resize(feature, rois) @ (W_fc @ [W_loc|W_score])
//                + (b_fc @ [W_loc|W_score] + [b_loc|b_score])
// 413 GF -> 32 GF. Floor: 411 MB W_fc + 100 MB pool = ~81 us HBM.
// R5: gemm1 A-path made COALESCED — R1..R4 all loaded A fragments direct
// (lane=row scatter: 16 rows/instr, 16B per 64B line => TA-divergence cap
// ~2.6 TB/s). Now: dense global->reg (4 full rows/instr), cvt, swizzled
// ds_write; frags via conflict-free ds_read_b128. Pool: next-cell prefetch.
// ---------------------------------------------------------------------------

typedef float          f32x4 __attribute__((ext_vector_type(4)));
typedef __bf16         bfx8  __attribute__((ext_vector_type(8)));
typedef unsigned short u16x8 __attribute__((ext_vector_type(8)));
typedef unsigned short u16x4 __attribute__((ext_vector_type(4)));

#define KBIG 25088   // 7*7*512
#define NMID 4096    // FC_OUT
#define NROIS 2000
#define G1BLOCKS 784 // 392 m-tiles x 2 k-splits
#define SPLITS 28    // gemm2 K-splits (392 BK steps = 28*14)

__device__ __forceinline__ unsigned short f2bf(float f) {
  unsigned int u = __float_as_uint(f);
  return (unsigned short)((u + 0x7fffu + ((u >> 16) & 1u)) >> 16);
}

__device__ __forceinline__ void gll16(const void* g, void* l) {
  __builtin_amdgcn_global_load_lds(
      (const __attribute__((address_space(1))) void*)(uintptr_t)(g),
      (__attribute__((address_space(3))) void*)(uintptr_t)(l), 16, 0, 0);
}

// ---------------------------------------------------------------------------
// prep: blocks 0..2047 build WcatT[128][4096] bf16 (zero-padded cols>=105);
//       blocks 2048..2175 compute bc[c] = b_fc . Wcat[:,c] + bias[c].
// ---------------------------------------------------------------------------
__global__ __launch_bounds__(256) void k_prep(const float* __restrict__ Wl,
                                              const float* __restrict__ Ws,
                                              const float* __restrict__ bfc,
                                              const float* __restrict__ bl,
                                              const float* __restrict__ bs,
                                              unsigned short* __restrict__ WcatT,
                                              float* __restrict__ bc) {
  if (blockIdx.x < 2048) {
    int idx = blockIdx.x * 256 + threadIdx.x;
    int c = idx >> 12, k = idx & 4095;
    float v = 0.0f;
    if (c < 84)       v = Wl[k * 84 + c];
    else if (c < 105) v = Ws[k * 21 + (c - 84)];
    WcatT[idx] = f2bf(v);
  } else {
    int c = blockIdx.x - 2048;   // 0..127
    int t = threadIdx.x;
    __shared__ float red[256];
    float p = 0.0f;
    if (c < 105) {
      for (int k = t; k < 4096; k += 256) {
        float w = (c < 84) ? Wl[k * 84 + c] : Ws[k * 21 + (c - 84)];
        p += bfc[k] * w;
      }
    }
    red[t] = p;
    __syncthreads();
    for (int s = 128; s > 0; s >>= 1) {
      if (t < s) red[t] += red[t + s];
      __syncthreads();
    }
    if (t == 0) {
      float bias = (c < 84) ? bl[c] : (c < 105 ? bs[c - 84] : 0.0f);
      bc[c] = (c < 105) ? (red[0] + bias) : 0.0f;
    }
  }
}

// ---------------------------------------------------------------------------
// Fused: blocks [0,784) = GEMM1 (mt = bx>>1, ksplit = bx&1), [784,2784) = pool.
// GEMM1: Pg1[sp][n][m] f32 partial of (W_fc @ WcatT^T)^T.
//   A: coalesced global->reg (instr = 4 dense rows x 256B), cvt to bf16,
//      XOR-swizzled ds_write into sA[2][64][64] bf16 (dbuf).
//   B: gll16 into sB[2][128][64] bf16, pre-inverse-swizzled source.
//   Schedule per phase: putA(c+1) [implicit wait retires B(c)], stageB(c+1),
//   loadA(c+2), vmcnt(8)+lgkmcnt(0), s_barrier, compute(c), s_barrier.
//   vmcnt(8) = B(c+1)4 + A(c+2)4 in flight — no drain in the loop.
// ---------------------------------------------------------------------------
__global__ __launch_bounds__(256, 3) void k_pool_gemm1(
    const float* __restrict__ F, const float* __restrict__ rois,
    const int* __restrict__ ihp, const int* __restrict__ iwp,
    unsigned short* __restrict__ A,
    const float* __restrict__ Wfc, const unsigned short* __restrict__ WcatT,
    float* __restrict__ Pg1) {
  const int t = threadIdx.x;
  __shared__ __align__(16) char sA[16384];   // [2][64 rows][128 B]
  __shared__ __align__(16) char sB[32768];   // [2][128 rows][128 B]
  if (blockIdx.x < G1BLOCKS) {
    // ---------------- GEMM1 ----------------
    const int lane = t & 63, wid = t >> 6;
    const int l15 = lane & 15, l4 = lane >> 4;
    const int mt = blockIdx.x >> 1, sp = blockIdx.x & 1;
    const int m0 = mt * 64;
    const int kbase = sp * 2048;
    const int jlog = (t & 7) ^ ((t >> 3) & 7);
    f32x4 acc[8] = {};
    f32x4 rE[4], rO[4];

    const float* abase = Wfc + (size_t)m0 * NMID + kbase;
    const int arw = t >> 4;          // row within 16-row group
    const int acl = (t & 15) * 4;    // float col
    const int ac16 = (t & 15) >> 1;  // 16B chunk within row
    const int ahalf = t & 1;         // 8B half of the chunk

    auto loadA = [&](f32x4* d, int c) {
#pragma unroll
      for (int i = 0; i < 4; ++i)
        d[i] = *(const f32x4*)(abase + (size_t)(i * 16 + arw) * NMID + c * 64 + acl);
    };
    auto putA = [&](const f32x4* r, int off) {
#pragma unroll
      for (int i = 0; i < 4; ++i) {
        const int row = i * 16 + arw;
        u16x4 p;
#pragma unroll
        for (int j = 0; j < 4; ++j) p[j] = f2bf(r[i][j]);
        *(u16x4*)(sA + off + row * 128 + ((ac16 ^ (row & 7)) << 4) + ahalf * 8) = p;
      }
    };
    auto stageB = [&](int c, int off) {
#pragma unroll
      for (int q = 0; q < 4; ++q)
        gll16(WcatT + (size_t)(q * 32 + (t >> 3)) * NMID + kbase + c * 64 + jlog * 8,
              sB + off + q * 4096 + wid * 1024);
    };
    auto compute = [&](int aoff, int boff) {
#pragma unroll
      for (int kk = 0; kk < 2; ++kk) {
        const int ar = wid * 16 + l15;
        bfx8 af = *(const bfx8*)(sA + aoff + ar * 128 + ((((kk << 2) + l4) ^ (ar & 7)) << 4));
        bfx8 bfr[8];
#pragma unroll
        for (int nt = 0; nt < 8; ++nt) {
          const int row = nt * 16 + l15;
          bfr[nt] = *(const bfx8*)(sB + boff + row * 128 + ((((kk << 2) + l4) ^ (row & 7)) << 4));
        }
#pragma unroll
        for (int nt = 0; nt < 8; ++nt)
          acc[nt] = __builtin_amdgcn_mfma_f32_16x16x32_bf16(af, bfr[nt], acc[nt], 0, 0, 0);
      }
    };

    // prologue: issue order A(0) < B(0) < A(1); putA(0) waits only A(0)
    loadA(rE, 0);
    __builtin_amdgcn_sched_barrier(0);
    stageB(0, 0);
    __builtin_amdgcn_sched_barrier(0);
    loadA(rO, 1);
    __builtin_amdgcn_sched_barrier(0);
    putA(rE, 0);

    for (int cc = 0; cc < 16; ++cc) {
      const int c0 = cc * 2;
      // even: compute c0 (buf0); prep c0+1 (buf1); load A(c0+2) -> rE
      putA(rO, 8192);                       // implicit wait A(c0+1) retires B(c0)
      stageB((c0 + 1 < 32) ? c0 + 1 : 31, 16384);
      __builtin_amdgcn_sched_barrier(0);
      loadA(rE, (c0 + 2 < 32) ? c0 + 2 : 31);
      __builtin_amdgcn_sched_barrier(0);
      asm volatile("s_waitcnt vmcnt(8) lgkmcnt(0)" ::: "memory");
      __builtin_amdgcn_s_barrier();
      __builtin_amdgcn_sched_barrier(0);
      compute(0, 0);
      __builtin_amdgcn_s_barrier();
      // odd: compute c0+1 (buf1); prep c0+2 (buf0); load A(c0+3) -> rO
      putA(rE, 0);
      stageB((c0 + 2 < 32) ? c0 + 2 : 31, 0);
      __builtin_amdgcn_sched_barrier(0);
      loadA(rO, (c0 + 3 < 32) ? c0 + 3 : 31);
      __builtin_amdgcn_sched_barrier(0);
      asm volatile("s_waitcnt vmcnt(8) lgkmcnt(0)" ::: "memory");
      __builtin_amdgcn_s_barrier();
      __builtin_amdgcn_sched_barrier(0);
      compute(8192, 16384);
      __builtin_amdgcn_s_barrier();
    }
    // epilogue: D col(lane&15)=n, row((lane>>4)*4+i)=m -> 16B f32 stores
#pragma unroll
    for (int nt = 0; nt < 8; ++nt) {
      const int n = nt * 16 + l15;
      float* dst = Pg1 + ((size_t)sp * 128 + n) * KBIG + m0 + wid * 16 + l4 * 4;
      *(f32x4*)dst = acc[nt];
    }
  } else {
    // ---------------- pool (next-cell prefetch) ----------------
    const int r = blockIdx.x - G1BLOCKS;
    const float ih = (float)ihp[0], iw = (float)iwp[0];
    const float y1 = rois[r * 4 + 0] / ih;
    const float x1 = rois[r * 4 + 1] / iw;
    const float y2 = rois[r * 4 + 2] / ih;
    const float x2 = rois[r * 4 + 3] / iw;
    const float sy = (y2 - y1) * 49.0f / 6.0f;
    const float sx = (x2 - x1) * 49.0f / 6.0f;
    const int ch = t * 2;
    unsigned int* __restrict__ Arow = (unsigned int*)(A + (size_t)r * KBIG);

    auto cellcoords = [&](int cell, int& o00, int& o01, int& o10, int& o11,
                          float& yl, float& xl, bool& valid) {
      const int iy = cell / 7, ix = cell - iy * 7;
      const float in_y = y1 * 49.0f + (float)iy * sy;
      const float in_x = x1 * 49.0f + (float)ix * sx;
      const float y0f = floorf(in_y), x0f = floorf(in_x);
      yl = in_y - y0f; xl = in_x - x0f;
      const int y0  = (int)fminf(fmaxf(y0f, 0.0f), 49.0f);
      const int y1i = (int)fminf(fmaxf(y0f + 1.0f, 0.0f), 49.0f);
      const int x0  = (int)fminf(fmaxf(x0f, 0.0f), 49.0f);
      const int x1i = (int)fminf(fmaxf(x0f + 1.0f, 0.0f), 49.0f);
      valid = (in_y >= 0.0f) && (in_y <= 49.0f) && (in_x >= 0.0f) && (in_x <= 49.0f);
      o00 = (y0 * 50 + x0) * 512;  o01 = (y0 * 50 + x1i) * 512;
      o10 = (y1i * 50 + x0) * 512; o11 = (y1i * 50 + x1i) * 512;
    };

    int o00, o01, o10, o11; float yl, xl; bool valid;
    cellcoords(0, o00, o01, o10, o11, yl, xl, valid);
    float2 f00 = *(const float2*)&F[o00 + ch];
    float2 f01 = *(const float2*)&F[o01 + ch];
    float2 f10 = *(const float2*)&F[o10 + ch];
    float2 f11 = *(const float2*)&F[o11 + ch];

    for (int cell = 0; cell < 49; ++cell) {
      const float2 g00 = f00, g01 = f01, g10 = f10, g11 = f11;
      const float pyl = yl, pxl = xl;
      const bool pv = valid;
      if (cell < 48) {
        cellcoords(cell + 1, o00, o01, o10, o11, yl, xl, valid);
        f00 = *(const float2*)&F[o00 + ch];
        f01 = *(const float2*)&F[o01 + ch];
        f10 = *(const float2*)&F[o10 + ch];
        f11 = *(const float2*)&F[o11 + ch];
      }
      float oA = 0.0f, oB = 0.0f;
      if (pv) {
        float t0 = g00.x * (1.0f - pxl) + g01.x * pxl;
        float t1 = g00.y * (1.0f - pxl) + g01.y * pxl;
        float b0 = g10.x * (1.0f - pxl) + g11.x * pxl;
        float b1 = g10.y * (1.0f - pxl) + g11.y * pxl;
        oA = t0 * (1.0f - pyl) + b0 * pyl;
        oB = t1 * (1.0f - pyl) + b1 * pyl;
      }
      Arow[(cell * 512 + ch) >> 1] =
          (unsigned int)f2bf(oA) | ((unsigned int)f2bf(oB) << 16);
    }
  }
}

// ---------------------------------------------------------------------------
// addcvt: WcT[n][m] bf16 = Pg1[0][n][m] + Pg1[1][n][m]
// ---------------------------------------------------------------------------
__global__ __launch_bounds__(256) void k_addcvt(const float* __restrict__ Pg1,
                                                unsigned short* __restrict__ WcT) {
  const size_t i = ((size_t)blockIdx.x * 256 + threadIdx.x) * 8;  // < 128*25088
  f32x4 a0 = *(const f32x4*)(Pg1 + i);
  f32x4 a1 = *(const f32x4*)(Pg1 + i + 4);
  f32x4 b0 = *(const f32x4*)(Pg1 + 3211264 + i);
  f32x4 b1 = *(const f32x4*)(Pg1 + 3211264 + i + 4);
  u16x8 o;
#pragma unroll
  for (int j = 0; j < 4; ++j) {
    o[j]     = f2bf(a0[j] + b0[j]);
    o[j + 4] = f2bf(a1[j] + b1[j]);
  }
  *(u16x8*)(WcT + i) = o;
}

// ---------------------------------------------------------------------------
// GEMM2: P[mt*28+sp][64][128] f32 = pool_tile(mt) @ WcT_slice(sp).
// Counted-vmcnt double buffer: stage(c+1); vmcnt(6); barrier; compute(c);
// barrier. One 6-op staging group per region -> count is order-robust.
// ---------------------------------------------------------------------------
__global__ __launch_bounds__(256) void k_gemm2(const unsigned short* __restrict__ Ap,
                                               const unsigned short* __restrict__ WcT,
                                               float* __restrict__ P) {
  __shared__ __align__(16) char S[49152];
  const int t = threadIdx.x;
  const int lane = t & 63, wid = t >> 6;
  const int wm = wid >> 1, wn = wid & 1;
  const int l15 = lane & 15, l4 = lane >> 4;
  const int mt = blockIdx.x, sp = blockIdx.y;
  const int kbase = sp * 896;     // 14 BK-steps of 64
  const int jlog = (t & 7) ^ ((t >> 3) & 7);
  f32x4 acc[2][4] = {};

  int ar0 = mt * 64 + (t >> 3);
  int ar1 = ar0 + 32;
  if (ar0 > NROIS - 1) ar0 = NROIS - 1;
  if (ar1 > NROIS - 1) ar1 = NROIS - 1;
  const unsigned short* asrc0 = Ap + (size_t)ar0 * KBIG + jlog * 8;
  const unsigned short* asrc1 = Ap + (size_t)ar1 * KBIG + jlog * 8;

  auto stage2 = [&](int c, int off) {
    const int k0 = kbase + c * 64;
    gll16(asrc0 + k0, S + off + wid * 1024);
    gll16(asrc1 + k0, S + off + 4096 + wid * 1024);
#pragma unroll
    for (int q = 0; q < 4; ++q)
      gll16(WcT + (size_t)(q * 32 + (t >> 3)) * KBIG + k0 + jlog * 8,
            S + off + 8192 + q * 4096 + wid * 1024);
  };
  auto compute2 = [&](int off) {
#pragma unroll
    for (int kh = 0; kh < 2; ++kh) {
      bfx8 af[2], bfr[4];
#pragma unroll
      for (int mi = 0; mi < 2; ++mi) {
        const int row = wm * 32 + mi * 16 + l15;
        af[mi] = *(const bfx8*)(S + off + row * 128 + ((((kh << 2) + l4) ^ (row & 7)) << 4));
      }
#pragma unroll
      for (int ni = 0; ni < 4; ++ni) {
        const int row = wn * 64 + ni * 16 + l15;
        bfr[ni] = *(const bfx8*)(S + off + 8192 + row * 128 + ((((kh << 2) + l4) ^ (row & 7)) << 4));
      }
#pragma unroll
      for (int mi = 0; mi < 2; ++mi)
#pragma unroll
        for (int ni = 0; ni < 4; ++ni)
          acc[mi][ni] = __builtin_amdgcn_mfma_f32_16x16x32_bf16(af[mi], bfr[ni], acc[mi][ni], 0, 0, 0);
    }
  };

  stage2(0, 0);
  for (int cc = 0; cc < 7; ++cc) {
    const int c0 = cc * 2;
    stage2(c0 + 1, 24576);
    asm volatile("s_waitcnt vmcnt(6)" ::: "memory");
    __builtin_amdgcn_s_barrier();
    __builtin_amdgcn_sched_barrier(0);
    compute2(0);
    __builtin_amdgcn_s_barrier();
    stage2((c0 + 2 < 14) ? c0 + 2 : 13, 0);
    asm volatile("s_waitcnt vmcnt(6)" ::: "memory");
    __builtin_amdgcn_s_barrier();
    __builtin_amdgcn_sched_barrier(0);
    compute2(24576);
    __builtin_amdgcn_s_barrier();
  }
  asm volatile("s_waitcnt vmcnt(0)" ::: "memory");
  float* out = P + (size_t)(mt * SPLITS + sp) * 8192;
#pragma unroll
  for (int mi = 0; mi < 2; ++mi)
#pragma unroll
    for (int ni = 0; ni < 4; ++ni)
#pragma unroll
      for (int i = 0; i < 4; ++i)
        out[(wm * 32 + mi * 16 + l4 * 4 + i) * 128 + wn * 64 + ni * 16 + l15] = acc[mi][ni][i];
}

// ---------------------------------------------------------------------------
// reduce: sum 28 K-split partials + bias, scatter into the two outputs.
// ---------------------------------------------------------------------------
__global__ __launch_bounds__(128) void k_reduce(const float* __restrict__ P,
                                                const float* __restrict__ bc,
                                                float* __restrict__ out) {
  const int m = blockIdx.x;     // 0..1999
  const int c = threadIdx.x;    // 0..127
  if (c >= 105) return;
  const int mt = m >> 6, r = m & 63;
  float sum = 0.0f;
#pragma unroll
  for (int s = 0; s < SPLITS; ++s)
    sum += P[(size_t)(mt * SPLITS + s) * 8192 + r * 128 + c];
  sum += bc[c];
  if (c < 84) out[m * 84 + c] = sum;
  else        out[168000 + m * 21 + (c - 84)] = sum;
}

// ---------------------------------------------------------------------------
extern "C" void kernel_launch(void* const* d_in, const int* in_sizes, int n_in,
                              void* d_out, int out_size, void* d_ws, size_t ws_size,
                              hipStream_t stream) {
  const float* F    = (const float*)d_in[0];
  const float* rois = (const float*)d_in[1];
  const int*   ih   = (const int*)d_in[2];
  const int*   iw   = (const int*)d_in[3];
  const float* Wfc  = (const float*)d_in[4];
  const float* bfc  = (const float*)d_in[5];
  const float* Wl   = (const float*)d_in[6];
  const float* bl   = (const float*)d_in[7];
  const float* Ws   = (const float*)d_in[8];
  const float* bs   = (const float*)d_in[9];
  (void)in_sizes; (void)n_in; (void)out_size; (void)ws_size;

  char* ws = (char*)d_ws;
  // ws layout (bytes):
  //   pool  bf16 [2000][25088]      @ 0          (100,352,000)
  //   WcatT bf16 [128][4096]        @ 100352000  (1,048,576)
  //   WcT   bf16 [128][25088]       @ 101400576  (6,422,528)
  //   bc    f32  [128]              @ 107823104  (512)
  //   P     f32  [896][64][128]     @ 107823616  (29,360,128)
  //   Pg1   f32  [2][128][25088]    @ 137183744  (25,690,112)  total ~163 MB
  unsigned short* Apool = (unsigned short*)(ws);
  unsigned short* WcatT = (unsigned short*)(ws + 100352000);
  unsigned short* WcT   = (unsigned short*)(ws + 101400576);
  float*          bc    = (float*)(ws + 107823104);
  float*          P     = (float*)(ws + 107823616);
  float*          Pg1   = (float*)(ws + 137183744);
  float*          out   = (float*)d_out;

  k_prep      <<<2176, 256, 0, stream>>>(Wl, Ws, bfc, bl, bs, WcatT, bc);
  k_pool_gemm1<<<G1BLOCKS + NROIS, 256, 0, stream>>>(F, rois, ih, iw, Apool,
                                                     Wfc, WcatT, Pg1);
  k_addcvt    <<<1568, 256, 0, stream>>>(Pg1, WcT);
  k_gemm2     <<<dim3(32, SPLITS), 256, 0, stream>>>(Apool, WcT, P);
  k_reduce    <<<NROIS, 128, 0, stream>>>(P, bc, out);
}